// Round 2
// baseline (396.370 us; speedup 1.0000x reference)
//
#include <hip/hip_runtime.h>
#include <hip/hip_bf16.h>
#include <stdint.h>

typedef __bf16 bf16_t;
typedef __bf16 bf16x8 __attribute__((ext_vector_type(8)));
typedef float  f32x4  __attribute__((ext_vector_type(4)));
// 4-byte-aligned float4 (global dwordx4 only needs dword alignment on CDNA)
typedef float  f32x4u __attribute__((ext_vector_type(4), aligned(4)));

constexpr int kS   = 49284;            // 222*222 pixels per (b,c) plane
constexpr int kCout = 64;
constexpr int kK   = 288;              // C_in * 9
constexpr int kB   = 16;
constexpr int kM   = kB * kS;          // 788544 output rows (= 64 * 12321)
constexpr int kBM  = 64;               // rows per block
constexpr int kImg = 32 * 224 * 224;   // floats per image = 1605632
constexpr unsigned kLim = (unsigned)kB * kImg - 8;  // fault-safe clamp

// weights fp32 [288][64] -> wt2 bf16 [64][288], K permuted: k' = tap*32 + t
__global__ void prep_weights(const float* __restrict__ w, bf16_t* __restrict__ wt2) {
    int e = blockIdx.x * 256 + threadIdx.x;
    if (e >= kCout * kK) return;
    int n = e / kK, kp = e - n * kK;
    int tap = kp >> 5, t = kp & 31;
    int f = t * 9 + tap;               // original K index
    wt2[e] = (bf16_t)w[f * kCout + n];
}

__global__ __launch_bounds__(256, 4) void conv_mfma(
        const float* __restrict__ x, const bf16_t* __restrict__ wt2,
        const float* __restrict__ bias, float* __restrict__ out) {
    __shared__ __align__(16) bf16_t sA[kBM * kK];   // [64 rows][288], tap-major K

    const int tid = threadIdx.x;
    const int m0  = blockIdx.x * kBM;

    // ---- staging: 2304 tasks = (row r, tap, t-quarter q8); 9 per thread ----
    #pragma unroll
    for (int it = 0; it < 9; ++it) {
        unsigned tsk = it * 256 + tid;
        unsigned r   = tsk / 36u;
        unsigned c36 = tsk - r * 36u;
        unsigned tap = c36 >> 2, q8 = c36 & 3;
        unsigned m   = m0 + r;
        unsigned b   = m / (unsigned)kS;
        unsigned s   = m - b * kS;
        unsigned pix0 = s * 32u + q8 * 8u;        // first of 8 consecutive pix
        unsigned cc  = pix0 / (unsigned)kS;       // input channel
        unsigned rem = pix0 - cc * kS;
        unsigned ii  = rem / 222u;
        unsigned jj  = rem - ii * 222u;
        unsigned A0  = pix0 + 892u * cc + 2u * ii;  // x-linear addr of (cc,ii,jj)
        int usplit   = 222 - (int)jj;               // row-crossing position (>8 = none)
        unsigned extra = (ii == 221u) ? 450u : 2u;  // addr skip at crossing (c vs i)
        unsigned di  = tap / 3u, dj = tap - di * 3u;
        unsigned fltA = b * (unsigned)kImg + A0 + di * 224u + dj;
        fltA = min(fltA, kLim);
        f32x4u a0 = *(const f32x4u*)(x + fltA);
        f32x4u a1 = *(const f32x4u*)(x + fltA + 4);
        f32x4u b0 = a0, b1 = a1;
        if (usplit < 8) {                          // rare (~3.6% of lanes)
            unsigned fltB = min(fltA + extra, kLim);
            b0 = *(const f32x4u*)(x + fltB);
            b1 = *(const f32x4u*)(x + fltB + 4);
        }
        float va[8] = {a0.x, a0.y, a0.z, a0.w, a1.x, a1.y, a1.z, a1.w};
        float vb[8] = {b0.x, b0.y, b0.z, b0.w, b1.x, b1.y, b1.z, b1.w};
        bf16x8 frag;
        #pragma unroll
        for (int u = 0; u < 8; ++u)
            frag[u] = (bf16_t)((u < usplit) ? va[u] : vb[u]);
        *(bf16x8*)(sA + r * kK + tap * 32u + q8 * 8u) = frag;   // 16B aligned
    }

    // ---- per-wave weight fragments (A operand), 9 taps, from L2-hot wt2 ----
    const int wv   = tid >> 6;
    const int lane = tid & 63;
    const int lc   = lane & 15;
    const int q    = lane >> 4;

    bf16x8 afr[9];
    #pragma unroll
    for (int tap = 0; tap < 9; ++tap)
        afr[tap] = *(const bf16x8*)(wt2 + (wv * 16 + lc) * kK + tap * 32 + q * 8);

    __syncthreads();

    // ---- MFMA: D[n(16)][pix(16)]; K = 9 taps x 32 ----
    f32x4 acc[4] = {};
    #pragma unroll
    for (int pg = 0; pg < 4; ++pg) {
        const bf16_t* bx = sA + (pg * 16 + lc) * kK;
        #pragma unroll
        for (int tap = 0; tap < 9; ++tap) {
            bf16x8 bfrag = *(const bf16x8*)(bx + tap * 32 + q * 8);
            acc[pg] = __builtin_amdgcn_mfma_f32_16x16x32_bf16(afr[tap], bfrag, acc[pg], 0, 0, 0);
        }
    }

    // ---- epilogue: col(lane&15)=pixel -> coalesced stores over s ----
    #pragma unroll
    for (int pg = 0; pg < 4; ++pg) {
        int m = m0 + pg * 16 + lc;
        int b = m / kS;
        int s = m - b * kS;
        float* op = out + (b * kCout) * kS + s;
        #pragma unroll
        for (int reg = 0; reg < 4; ++reg) {
            int n = wv * 16 + q * 4 + reg;
            op[n * kS] = acc[pg][reg] + bias[n];
        }
    }
}

extern "C" void kernel_launch(void* const* d_in, const int* in_sizes, int n_in,
                              void* d_out, int out_size, void* d_ws, size_t ws_size,
                              hipStream_t stream) {
    (void)in_sizes; (void)n_in; (void)out_size; (void)ws_size;
    const float* x    = (const float*)d_in[0];
    const float* w    = (const float*)d_in[1];
    const float* bias = (const float*)d_in[2];
    float*       out  = (float*)d_out;
    bf16_t*      wt2  = (bf16_t*)d_ws;   // 64*288*2 = 36864 B

    prep_weights<<<(kCout * kK + 255) / 256, 256, 0, stream>>>(w, wt2);
    conv_mfma<<<kM / kBM, 256, 0, stream>>>(x, wt2, bias, out);
}